// Round 1
// baseline (237.078 us; speedup 1.0000x reference)
//
#include <hip/hip_runtime.h>

// GCN(2 layers, 7 nodes) + linear head + KAN (56 per-feature MLPs) + g-MLP, fused.
// B = 32768. Block = 256 threads = 4 waves, handles 64 batch elements (lane = elem).
// Waves split the 56 KAN feature nets (14 each); partial g1/lin1 accumulators
// reduced through LDS. All weight loads wave-uniform (readfirstlane) -> s_load.

#define NB 32768
#define ELEMS 64
#define XS_STRIDE 113   // 112 floats per elem, pad to 113 (odd -> conflict-free)
#define FS_STRIDE 57    // 56 floats per elem, pad to 57

__global__ __launch_bounds__(256, 2)
void gcn_kan_fused(const float* __restrict__ x,
                   const int*   __restrict__ edge,
                   const float* __restrict__ gcn1_w, const float* __restrict__ gcn1_b,
                   const float* __restrict__ gcn2_w, const float* __restrict__ gcn2_b,
                   const float* __restrict__ phi_w1, const float* __restrict__ phi_b1,
                   const float* __restrict__ phi_w2, const float* __restrict__ phi_b2,
                   const float* __restrict__ phi_w3, const float* __restrict__ phi_b3,
                   const float* __restrict__ g_w1,   const float* __restrict__ g_b1,
                   const float* __restrict__ g_w2,   const float* __restrict__ g_b2,
                   const float* __restrict__ g_w3,   const float* __restrict__ g_b3,
                   const float* __restrict__ line_w1,const float* __restrict__ line_b1,
                   const float* __restrict__ line_w2,const float* __restrict__ line_b2,
                   float* __restrict__ out)
{
    // LDS: region sU is reused: [x-stage 64*113 | h1 64*57] then [red 4*64*57]
    __shared__ float sU[4 * ELEMS * FS_STRIDE];       // 14592 floats = 58.4 KB
    __shared__ float sflat[ELEMS * FS_STRIDE];        // 14.6 KB
    __shared__ float Ahs[49];
    __shared__ float dinvs[8];

    float* xs  = sU;                       // [64][113] (7232 floats)
    float* h1s = sU + ELEMS * XS_STRIDE;   // [64][57]  (ends at 10880 < 14592)
    float* red = sU;                       // [4][64][57]

    const int t    = threadIdx.x;
    const int lane = t & 63;
    const int wave = t >> 6;
    const int e0   = blockIdx.x * ELEMS;

    // ---- Phase A: cooperative coalesced x load: 64*112 floats ----
    const float4* xblk = (const float4*)(x + (size_t)e0 * 112);
    for (int i = t; i < ELEMS * 28; i += 256) {       // 112/4 = 28 float4 per elem
        float4 v = xblk[i];
        int e = i / 28;
        int c = (i - e * 28) * 4;
        float* d = &xs[e * XS_STRIDE + c];
        d[0] = v.x; d[1] = v.y; d[2] = v.z; d[3] = v.w;
    }

    // ---- Phase B: build normalized adjacency A_hat in LDS ----
    if (t < 49) Ahs[t] = ((t / 7) == (t % 7)) ? 1.0f : 0.0f;   // self loops
    __syncthreads();
    if (t == 0) {
        #pragma unroll 1
        for (int e = 0; e < 14; ++e)
            Ahs[edge[14 + e] * 7 + edge[e]] = 1.0f;            // A[dst][src] = 1
    }
    __syncthreads();
    if (t < 7) {
        float s = 0.f;
        #pragma unroll
        for (int m = 0; m < 7; ++m) s += Ahs[t * 7 + m];
        dinvs[t] = rsqrtf(s);
    }
    __syncthreads();
    if (t < 49) Ahs[t] *= dinvs[t / 7] * dinvs[t % 7];
    __syncthreads();

    // ---- Phase C: GCN layer 1 (waves split nodes) ----
    for (int n4 = wave; n4 < 7; n4 += 4) {
        const int n = __builtin_amdgcn_readfirstlane(n4);
        float arow[7];
        #pragma unroll
        for (int m = 0; m < 7; ++m) arow[m] = Ahs[n * 7 + m];
        float ax[16];
        #pragma unroll
        for (int f = 0; f < 16; ++f) {
            float s = 0.f;
            #pragma unroll
            for (int m = 0; m < 7; ++m)
                s = fmaf(arow[m], xs[lane * XS_STRIDE + m * 16 + f], s);
            ax[f] = s;
        }
        #pragma unroll
        for (int c = 0; c < 8; ++c) {
            float s = gcn1_b[c];
            #pragma unroll
            for (int f = 0; f < 16; ++f) s = fmaf(ax[f], gcn1_w[f * 8 + c], s);
            h1s[lane * FS_STRIDE + n * 8 + c] = fmaxf(s, 0.f);
        }
    }
    __syncthreads();

    // ---- Phase D: GCN layer 2 -> sflat ----
    for (int n4 = wave; n4 < 7; n4 += 4) {
        const int n = __builtin_amdgcn_readfirstlane(n4);
        float arow[7];
        #pragma unroll
        for (int m = 0; m < 7; ++m) arow[m] = Ahs[n * 7 + m];
        float ah[8];
        #pragma unroll
        for (int cc = 0; cc < 8; ++cc) {
            float s = 0.f;
            #pragma unroll
            for (int m = 0; m < 7; ++m)
                s = fmaf(arow[m], h1s[lane * FS_STRIDE + m * 8 + cc], s);
            ah[cc] = s;
        }
        #pragma unroll
        for (int c = 0; c < 8; ++c) {
            float s = gcn2_b[c];
            #pragma unroll
            for (int cc = 0; cc < 8; ++cc) s = fmaf(ah[cc], gcn2_w[cc * 8 + c], s);
            sflat[lane * FS_STRIDE + n * 8 + c] = fmaxf(s, 0.f);
        }
    }
    __syncthreads();   // xs/h1s dead from here; red may overwrite

    // ---- Phase E: KAN phi-nets, 14 k's per wave; accumulate g1/lin1 partials ----
    float g1a[32];
    #pragma unroll
    for (int j = 0; j < 32; ++j) g1a[j] = 0.f;
    float lina[24];
    #pragma unroll
    for (int j = 0; j < 24; ++j) lina[j] = 0.f;

    const int kbase = __builtin_amdgcn_readfirstlane(wave * 14);
    #pragma unroll 1
    for (int kk = 0; kk < 14; ++kk) {
        const int k = kbase + kk;                 // wave-uniform (SGPR)
        const float f = sflat[lane * FS_STRIDE + k];

        float p1[32];
        #pragma unroll
        for (int i = 0; i < 32; ++i)
            p1[i] = fmaxf(fmaf(f, phi_w1[k * 32 + i], phi_b1[k * 32 + i]), 0.f);

        float p2[32];
        #pragma unroll
        for (int o = 0; o < 32; ++o) p2[o] = phi_b2[k * 32 + o];

        const float* __restrict__ w2k = phi_w2 + k * 1024;
        #pragma unroll 4
        for (int i = 0; i < 32; ++i) {
            const float a = p1[i];
            #pragma unroll
            for (int o = 0; o < 32; ++o)
                p2[o] = fmaf(a, w2k[i * 32 + o], p2[o]);
        }

        float ph = phi_b3[k];
        #pragma unroll
        for (int o = 0; o < 32; ++o)
            ph = fmaf(fmaxf(p2[o], 0.f), phi_w3[k * 32 + o], ph);

        #pragma unroll
        for (int j = 0; j < 32; ++j) g1a[j] = fmaf(ph, g_w1[k * 32 + j], g1a[j]);
        #pragma unroll
        for (int j = 0; j < 24; ++j) lina[j] = fmaf(f, line_w1[k * 24 + j], lina[j]);
    }

    // ---- Phase F: cross-wave reduce of g1 (32) + lin1 (24) partials ----
    {
        float* my = red + (wave * ELEMS + lane) * FS_STRIDE;
        #pragma unroll
        for (int j = 0; j < 32; ++j) my[j] = g1a[j];
        #pragma unroll
        for (int j = 0; j < 24; ++j) my[32 + j] = lina[j];
    }
    __syncthreads();
    {
        const int e = lane, part = wave;          // each thread sums 14 of the 56
        #pragma unroll
        for (int j = part * 14; j < part * 14 + 14; ++j) {
            float s = red[(0 * ELEMS + e) * FS_STRIDE + j]
                    + red[(1 * ELEMS + e) * FS_STRIDE + j]
                    + red[(2 * ELEMS + e) * FS_STRIDE + j]
                    + red[(3 * ELEMS + e) * FS_STRIDE + j];
            red[e * FS_STRIDE + j] = s;
        }
    }
    __syncthreads();

    // ---- Phase G: g-MLP + linear head tail (wave 0 only, one elem per lane) ----
    if (wave == 0) {
        const float* acc = red + lane * FS_STRIDE;
        float g1[32];
        #pragma unroll
        for (int j = 0; j < 32; ++j) g1[j] = fmaxf(acc[j] + g_b1[j], 0.f);

        float kan = g_b3[0];
        #pragma unroll
        for (int o = 0; o < 32; ++o) {
            float s = g_b2[o];
            #pragma unroll
            for (int i = 0; i < 32; ++i) s = fmaf(g1[i], g_w2[i * 32 + o], s);
            kan = fmaf(fmaxf(s, 0.f), g_w3[o], kan);
        }

        float lin = line_b2[0];
        #pragma unroll
        for (int j = 0; j < 24; ++j)
            lin = fmaf(fmaxf(acc[32 + j] + line_b1[j], 0.f), line_w2[j], lin);

        out[e0 + lane] = 0.5f * (lin + kan);
    }
}

extern "C" void kernel_launch(void* const* d_in, const int* in_sizes, int n_in,
                              void* d_out, int out_size, void* d_ws, size_t ws_size,
                              hipStream_t stream) {
    const float* x       = (const float*)d_in[0];
    const int*   edge    = (const int*)  d_in[1];
    const float* gcn1_w  = (const float*)d_in[2];
    const float* gcn1_b  = (const float*)d_in[3];
    const float* gcn2_w  = (const float*)d_in[4];
    const float* gcn2_b  = (const float*)d_in[5];
    const float* phi_w1  = (const float*)d_in[6];
    const float* phi_b1  = (const float*)d_in[7];
    const float* phi_w2  = (const float*)d_in[8];
    const float* phi_b2  = (const float*)d_in[9];
    const float* phi_w3  = (const float*)d_in[10];
    const float* phi_b3  = (const float*)d_in[11];
    const float* g_w1    = (const float*)d_in[12];
    const float* g_b1    = (const float*)d_in[13];
    const float* g_w2    = (const float*)d_in[14];
    const float* g_b2    = (const float*)d_in[15];
    const float* g_w3    = (const float*)d_in[16];
    const float* g_b3    = (const float*)d_in[17];
    const float* line_w1 = (const float*)d_in[18];
    const float* line_b1 = (const float*)d_in[19];
    const float* line_w2 = (const float*)d_in[20];
    const float* line_b2 = (const float*)d_in[21];
    float* out = (float*)d_out;

    dim3 grid(NB / ELEMS);   // 512 blocks
    dim3 block(256);
    gcn_kan_fused<<<grid, block, 0, stream>>>(
        x, edge, gcn1_w, gcn1_b, gcn2_w, gcn2_b,
        phi_w1, phi_b1, phi_w2, phi_b2, phi_w3, phi_b3,
        g_w1, g_b1, g_w2, g_b2, g_w3, g_b3,
        line_w1, line_b1, line_w2, line_b2, out);
}